// Round 6
// baseline (626.901 us; speedup 1.0000x reference)
//
#include <hip/hip_runtime.h>
#include <hip/hip_bf16.h>

#define NN 100000
#define NE 1600000
#define HID 64
#define SCAN_BS 256
#define NBLK ((NN + SCAN_BS - 1) / SCAN_BS)   // 391

typedef float f32x4 __attribute__((ext_vector_type(4)));
typedef float f32x2 __attribute__((ext_vector_type(2)));
typedef short bf16x8 __attribute__((ext_vector_type(8)));

__device__ __forceinline__ float bflo(unsigned u) { return __uint_as_float(u << 16); }
__device__ __forceinline__ float bfhi(unsigned u) { return __uint_as_float(u & 0xffff0000u); }
__device__ __forceinline__ unsigned short f2bf(float f) {
    __hip_bfloat16 h = (__hip_bfloat16)f;
    return *(unsigned short*)&h;
}

// ---------- x -> bf16 ----------
__global__ void xcast(const float* __restrict__ in, unsigned short* __restrict__ out, int n4) {
    int i = blockIdx.x * blockDim.x + threadIdx.x;
    if (i >= n4) return;
    float4 v = ((const float4*)in)[i];
    ushort4 o;
    o.x = f2bf(v.x); o.y = f2bf(v.y); o.z = f2bf(v.z); o.w = f2bf(v.w);
    ((ushort4*)out)[i] = o;
}

// ---------- CSR build ----------
__global__ void count_kernel(const int* __restrict__ dst, int* __restrict__ degI, int nE) {
    int e = blockIdx.x * blockDim.x + threadIdx.x;
    if (e < nE) atomicAdd(&degI[dst[e]], 1);
}

__global__ void scan1_kernel(const int* __restrict__ degI, int* __restrict__ rowtmp,
                             int* __restrict__ blockSum) {
    __shared__ int tmp[SCAN_BS];
    int t = threadIdx.x;
    int i = blockIdx.x * SCAN_BS + t;
    int d = (i < NN) ? degI[i] : 0;
    tmp[t] = d;
    __syncthreads();
    for (int off = 1; off < SCAN_BS; off <<= 1) {
        int v = (t >= off) ? tmp[t - off] : 0;
        __syncthreads();
        tmp[t] += v;
        __syncthreads();
    }
    if (i < NN) rowtmp[i] = tmp[t] - d;
    if (t == SCAN_BS - 1) blockSum[blockIdx.x] = tmp[t];
}

__global__ void scan2_kernel(const int* __restrict__ blockSum, int* __restrict__ blockOff, int n) {
    __shared__ int tmp[512];
    int t = threadIdx.x;
    tmp[t] = (t < n) ? blockSum[t] : 0;
    __syncthreads();
    for (int off = 1; off < 512; off <<= 1) {
        int v = (t >= off) ? tmp[t - off] : 0;
        __syncthreads();
        tmp[t] += v;
        __syncthreads();
    }
    if (t < n) blockOff[t] = (t == 0) ? 0 : tmp[t - 1];
}

// also initializes cursor = row_ptr so fill_kernel needs no row_ptr read / no memset
__global__ void scan3_kernel(const int* __restrict__ rowtmp, const int* __restrict__ blockOff,
                             int* __restrict__ row_ptr, int* __restrict__ cursor) {
    int i = blockIdx.x * SCAN_BS + threadIdx.x;
    if (i < NN) {
        int v = rowtmp[i] + blockOff[blockIdx.x];
        row_ptr[i] = v;
        cursor[i] = v;
    }
}

__global__ void fill_kernel(const int* __restrict__ src, const int* __restrict__ dst,
                            int* __restrict__ cursor, int* __restrict__ csr_src, int nE) {
    int e = blockIdx.x * blockDim.x + threadIdx.x;
    if (e >= nE) return;
    int d = dst[e];
    int pos = atomicAdd(&cursor[d], 1);
    csr_src[pos] = src[e];
}

// ---------- pure gather/mean (one wave per node, uint4 loads, shuffle reduce) ----------
template <int IN>
__launch_bounds__(256)
__global__ void aggregate(const int* __restrict__ row_ptr, const int* __restrict__ degI,
                          const int* __restrict__ csr_src,
                          const unsigned short* __restrict__ hin,
                          float* __restrict__ mout) {
    constexpr int LPE = IN / 8;
    constexpr int SPLIT = 64 / LPE;
    constexpr int UN = (IN == 64) ? 2 : 1;
    int g = threadIdx.x >> 6;
    int lane = threadIdx.x & 63;
    int node = blockIdx.x * 4 + g;         // grid sized so node < NN always
    int lane_p = lane & (LPE - 1);
    int sub = lane / LPE;

    float acc[8];
#pragma unroll
    for (int i = 0; i < 8; ++i) acc[i] = 0.f;

    int start = row_ptr[node];
    int dg = degI[node];
    const int* cs = csr_src + start;

    int e = sub;
    for (; e + SPLIT * (UN - 1) < dg; e += SPLIT * UN) {
        uint4 u[UN];
#pragma unroll
        for (int j = 0; j < UN; ++j) {
            int s = cs[e + SPLIT * j];
            u[j] = *(const uint4*)(hin + (size_t)s * IN + 8 * lane_p);
        }
#pragma unroll
        for (int j = 0; j < UN; ++j) {
            acc[0] += bflo(u[j].x); acc[1] += bfhi(u[j].x);
            acc[2] += bflo(u[j].y); acc[3] += bfhi(u[j].y);
            acc[4] += bflo(u[j].z); acc[5] += bfhi(u[j].z);
            acc[6] += bflo(u[j].w); acc[7] += bfhi(u[j].w);
        }
    }
    for (; e < dg; e += SPLIT) {
        int s = cs[e];
        uint4 u = *(const uint4*)(hin + (size_t)s * IN + 8 * lane_p);
        acc[0] += bflo(u.x); acc[1] += bfhi(u.x);
        acc[2] += bflo(u.y); acc[3] += bfhi(u.y);
        acc[4] += bflo(u.z); acc[5] += bfhi(u.z);
        acc[6] += bflo(u.w); acc[7] += bfhi(u.w);
    }

    // reduce across the SPLIT sub-groups (lanes LPE apart and up)
#pragma unroll
    for (int m = LPE; m < 64; m <<= 1) {
#pragma unroll
        for (int i = 0; i < 8; ++i) acc[i] += __shfl_xor(acc[i], m);
    }
    if (sub == 0) {
        float r = 1.0f / fmaxf((float)dg, 1.0f);
        float4 v0, v1;
        v0.x = acc[0] * r; v0.y = acc[1] * r; v0.z = acc[2] * r; v0.w = acc[3] * r;
        v1.x = acc[4] * r; v1.y = acc[5] * r; v1.z = acc[6] * r; v1.w = acc[7] * r;
        float* p = mout + (size_t)node * IN + 8 * lane_p;
        *(float4*)p = v0;
        *(float4*)(p + 4) = v1;
    }
}

// ---------- weight prep: f32 [K][64] -> packed bf16 hi/lo B-fragments ----------
__global__ void wprep(const float* __restrict__ Wl0, const float* __restrict__ Wr0,
                      const float* __restrict__ Wl1, const float* __restrict__ Wr1,
                      const float* __restrict__ Wl2, const float* __restrict__ Wr2,
                      const float* __restrict__ W1, unsigned short* __restrict__ out) {
    int b = blockIdx.x;
    int mid, local;
    if (b < 2) { mid = b; local = 0; }                  // K=32 matrices: 1 block each
    else { mid = 2 + (b - 2) / 2; local = (b - 2) & 1; } // K=64 matrices: 2 blocks each
    const float* Ws[8] = {Wl0, Wr0, Wl1, Wr1, Wl2, Wr2, W1, W1 + 64 * 64};
    const int offs[8] = {0, 4096, 8192, 16384, 24576, 32768, 40960, 49152};
    const float* W = Ws[mid];
    int e = local * 256 + threadIdx.x;   // entry = (ks*4+nt)*64 + lane
    int lane = e & 63;
    int fi = e >> 6;                     // ks*4 + nt
    int ks = fi >> 2, nt = fi & 3;
    int lg = lane >> 4, col = lane & 15;
    unsigned short hi[8], lo[8];
#pragma unroll
    for (int j = 0; j < 8; ++j) {
        float w = W[(ks * 32 + lg * 8 + j) * 64 + nt * 16 + col];
        unsigned short h = f2bf(w);
        hi[j] = h;
        lo[j] = f2bf(w - bflo(h));
    }
    unsigned short* dh = out + offs[mid] + ((size_t)(fi * 2 + 0) * 64 + lane) * 8;
    unsigned short* dl = out + offs[mid] + ((size_t)(fi * 2 + 1) * 64 + lane) * 8;
#pragma unroll
    for (int j = 0; j < 8; ++j) { dh[j] = hi[j]; dl[j] = lo[j]; }
}

// ---------- MFMA GEMM: hout = act( mean@Wl + bl + hroot@Wr ) ----------
template <int KIN, bool RELU>
__launch_bounds__(256)
__global__ void sage_gemm(const float* __restrict__ meanv,
                          const unsigned short* __restrict__ hroot,
                          const unsigned short* __restrict__ wl_pk,
                          const unsigned short* __restrict__ wr_pk,
                          const float* __restrict__ bl,
                          unsigned short* __restrict__ hout) {
    constexpr int NKS = KIN / 32;
    int wid = threadIdx.x >> 6, lane = threadIdx.x & 63;
    int tile = blockIdx.x * 4 + wid;
    if (tile >= NN / 16) return;
    int m0 = tile * 16;
    int ar = lane & 15;     // A row / D col
    int lg = lane >> 4;

    bf16x8 ah[NKS];
#pragma unroll
    for (int ks = 0; ks < NKS; ++ks)
        ah[ks] = *(const bf16x8*)(hroot + (size_t)(m0 + ar) * KIN + ks * 32 + lg * 8);

    bf16x8 amh[NKS], aml[NKS];
#pragma unroll
    for (int ks = 0; ks < NKS; ++ks) {
        const float* p = meanv + (size_t)(m0 + ar) * KIN + ks * 32 + lg * 8;
        float4 v0 = *(const float4*)p;
        float4 v1 = *(const float4*)(p + 4);
        float mv[8] = {v0.x, v0.y, v0.z, v0.w, v1.x, v1.y, v1.z, v1.w};
#pragma unroll
        for (int j = 0; j < 8; ++j) {
            unsigned short h = f2bf(mv[j]);
            amh[ks][j] = (short)h;
            aml[ks][j] = (short)f2bf(mv[j] - bflo(h));
        }
    }

#pragma unroll
    for (int nt = 0; nt < 4; ++nt) {
        f32x4 acc = {0.f, 0.f, 0.f, 0.f};
#pragma unroll
        for (int ks = 0; ks < NKS; ++ks) {
            int fi = ks * 4 + nt;
            bf16x8 wlh = *(const bf16x8*)(wl_pk + ((size_t)(fi * 2 + 0) * 64 + lane) * 8);
            bf16x8 wll = *(const bf16x8*)(wl_pk + ((size_t)(fi * 2 + 1) * 64 + lane) * 8);
            bf16x8 wrh = *(const bf16x8*)(wr_pk + ((size_t)(fi * 2 + 0) * 64 + lane) * 8);
            bf16x8 wrl = *(const bf16x8*)(wr_pk + ((size_t)(fi * 2 + 1) * 64 + lane) * 8);
            acc = __builtin_amdgcn_mfma_f32_16x16x32_bf16(amh[ks], wlh, acc, 0, 0, 0);
            acc = __builtin_amdgcn_mfma_f32_16x16x32_bf16(amh[ks], wll, acc, 0, 0, 0);
            acc = __builtin_amdgcn_mfma_f32_16x16x32_bf16(aml[ks], wlh, acc, 0, 0, 0);
            acc = __builtin_amdgcn_mfma_f32_16x16x32_bf16(ah[ks],  wrh, acc, 0, 0, 0);
            acc = __builtin_amdgcn_mfma_f32_16x16x32_bf16(ah[ks],  wrl, acc, 0, 0, 0);
        }
        float b = bl[nt * 16 + ar];
#pragma unroll
        for (int r = 0; r < 4; ++r) {
            float o = acc[r] + b;
            if (RELU) o = fmaxf(o, 0.f);
            hout[(size_t)(m0 + lg * 4 + r) * 64 + nt * 16 + ar] = f2bf(o);
        }
    }
}

// ---------- a1/a2 = h2 @ W1[0:64], h2 @ W1[64:128] ----------
__launch_bounds__(256)
__global__ void pred_gemm(const unsigned short* __restrict__ h2,
                          const unsigned short* __restrict__ wa_pk,
                          const unsigned short* __restrict__ wb_pk,
                          unsigned short* __restrict__ a1,
                          unsigned short* __restrict__ a2) {
    int wid = threadIdx.x >> 6, lane = threadIdx.x & 63;
    int tile = blockIdx.x * 4 + wid;
    if (tile >= NN / 16) return;
    int m0 = tile * 16;
    int ar = lane & 15;
    int lg = lane >> 4;
    bf16x8 ah[2];
#pragma unroll
    for (int ks = 0; ks < 2; ++ks)
        ah[ks] = *(const bf16x8*)(h2 + (size_t)(m0 + ar) * 64 + ks * 32 + lg * 8);
#pragma unroll
    for (int nt = 0; nt < 4; ++nt) {
        f32x4 p = {0.f, 0.f, 0.f, 0.f};
        f32x4 q = {0.f, 0.f, 0.f, 0.f};
#pragma unroll
        for (int ks = 0; ks < 2; ++ks) {
            int fi = ks * 4 + nt;
            bf16x8 wah = *(const bf16x8*)(wa_pk + ((size_t)(fi * 2 + 0) * 64 + lane) * 8);
            bf16x8 wal = *(const bf16x8*)(wa_pk + ((size_t)(fi * 2 + 1) * 64 + lane) * 8);
            bf16x8 wbh = *(const bf16x8*)(wb_pk + ((size_t)(fi * 2 + 0) * 64 + lane) * 8);
            bf16x8 wbl = *(const bf16x8*)(wb_pk + ((size_t)(fi * 2 + 1) * 64 + lane) * 8);
            p = __builtin_amdgcn_mfma_f32_16x16x32_bf16(ah[ks], wah, p, 0, 0, 0);
            p = __builtin_amdgcn_mfma_f32_16x16x32_bf16(ah[ks], wal, p, 0, 0, 0);
            q = __builtin_amdgcn_mfma_f32_16x16x32_bf16(ah[ks], wbh, q, 0, 0, 0);
            q = __builtin_amdgcn_mfma_f32_16x16x32_bf16(ah[ks], wbl, q, 0, 0, 0);
        }
#pragma unroll
        for (int r = 0; r < 4; ++r) {
            size_t off = (size_t)(m0 + lg * 4 + r) * 64 + nt * 16 + ar;
            a1[off] = f2bf(p[r]);
            a2[off] = f2bf(q[r]);
        }
    }
}

// ---------- edge predictor: one edge per lane, packed-f32 MLP (v_pk_fma_f32) ----------
__launch_bounds__(256)
__global__ void edge_pred(const int* __restrict__ src, const int* __restrict__ dst,
                          const unsigned short* __restrict__ a1, const unsigned short* __restrict__ a2,
                          const float* __restrict__ ea,
                          const float* __restrict__ W1, const float* __restrict__ b1,
                          const float* __restrict__ W2, const float* __restrict__ b2,
                          const float* __restrict__ W3, const float* __restrict__ b3,
                          float* __restrict__ out, int nE) {
    int e = blockIdx.x * blockDim.x + threadIdx.x;
    if (e >= nE) return;
    int s = src[e];
    int d = dst[e];

    const uint4* pa = (const uint4*)(a1 + (size_t)s * 64);
    const uint4* pb = (const uint4*)(a2 + (size_t)d * 64);
    const float4* eav = (const float4*)(ea + (size_t)e * 8);
    float4 v0 = eav[0];
    float4 v1 = eav[1];

    // z1 = ea @ W1e + b1  (pairs of output features; per-element order identical to scalar)
    f32x2 z1v[32];
    const float* wr = W1 + 128 * 64;
#pragma unroll
    for (int j = 0; j < 32; ++j) {
        f32x2 a = *(const f32x2*)(b1 + 2 * j);
        a = __builtin_elementwise_fma((f32x2){v0.x, v0.x}, *(const f32x2*)(wr + 2 * j), a);
        a = __builtin_elementwise_fma((f32x2){v0.y, v0.y}, *(const f32x2*)(wr + 64 + 2 * j), a);
        a = __builtin_elementwise_fma((f32x2){v0.z, v0.z}, *(const f32x2*)(wr + 128 + 2 * j), a);
        a = __builtin_elementwise_fma((f32x2){v0.w, v0.w}, *(const f32x2*)(wr + 192 + 2 * j), a);
        a = __builtin_elementwise_fma((f32x2){v1.x, v1.x}, *(const f32x2*)(wr + 256 + 2 * j), a);
        a = __builtin_elementwise_fma((f32x2){v1.y, v1.y}, *(const f32x2*)(wr + 320 + 2 * j), a);
        a = __builtin_elementwise_fma((f32x2){v1.z, v1.z}, *(const f32x2*)(wr + 384 + 2 * j), a);
        a = __builtin_elementwise_fma((f32x2){v1.w, v1.w}, *(const f32x2*)(wr + 448 + 2 * j), a);
        z1v[j] = a;
    }

    // + a1[s] + a2[d]
#pragma unroll
    for (int q = 0; q < 8; ++q) {
        uint4 ua = pa[q];
        uint4 ub = pb[q];
        int j0 = q * 4;
        z1v[j0 + 0] += (f32x2){bflo(ua.x) + bflo(ub.x), bfhi(ua.x) + bfhi(ub.x)};
        z1v[j0 + 1] += (f32x2){bflo(ua.y) + bflo(ub.y), bfhi(ua.y) + bfhi(ub.y)};
        z1v[j0 + 2] += (f32x2){bflo(ua.z) + bflo(ub.z), bfhi(ua.z) + bfhi(ub.z)};
        z1v[j0 + 3] += (f32x2){bflo(ua.w) + bflo(ub.w), bfhi(ua.w) + bfhi(ub.w)};
    }

    // z2 = relu(z1) @ W2 + b2   (fully unrolled: all register indices static)
    f32x2 z2v[16];
#pragma unroll
    for (int j = 0; j < 16; ++j) z2v[j] = *(const f32x2*)(b2 + 2 * j);
#pragma unroll
    for (int k = 0; k < 64; ++k) {
        float v = fmaxf(z1v[k >> 1][k & 1], 0.0f);
        f32x2 vv = {v, v};
        const float* w = W2 + (size_t)k * 32;
#pragma unroll
        for (int j = 0; j < 16; ++j)
            z2v[j] = __builtin_elementwise_fma(vv, *(const f32x2*)(w + 2 * j), z2v[j]);
    }

    // z3 = relu(z2) @ W3 + b3 (even/odd partial sums, one final add)
    f32x2 accp = {b3[0], 0.f};
#pragma unroll
    for (int j = 0; j < 16; ++j) {
        f32x2 r = {fmaxf(z2v[j][0], 0.f), fmaxf(z2v[j][1], 0.f)};
        accp = __builtin_elementwise_fma(r, *(const f32x2*)(W3 + 2 * j), accp);
    }
    float o = accp[0] + accp[1];

    out[e] = 1.0f / (1.0f + __expf(-o));
}

extern "C" void kernel_launch(void* const* d_in, const int* in_sizes, int n_in,
                              void* d_out, int out_size, void* d_ws, size_t ws_size,
                              hipStream_t stream) {
    const float* x   = (const float*)d_in[0];
    const int*   ei  = (const int*)d_in[1];
    const float* ea  = (const float*)d_in[2];
    const float* Wl0 = (const float*)d_in[3];
    const float* bl0 = (const float*)d_in[4];
    const float* Wr0 = (const float*)d_in[5];
    const float* Wl1 = (const float*)d_in[6];
    const float* bl1 = (const float*)d_in[7];
    const float* Wr1 = (const float*)d_in[8];
    const float* Wl2 = (const float*)d_in[9];
    const float* bl2 = (const float*)d_in[10];
    const float* Wr2 = (const float*)d_in[11];
    const float* W1  = (const float*)d_in[12];
    const float* b1  = (const float*)d_in[13];
    const float* W2  = (const float*)d_in[14];
    const float* b2  = (const float*)d_in[15];
    const float* W3  = (const float*)d_in[16];
    const float* b3  = (const float*)d_in[17];

    const int* src = ei;
    const int* dst = ei + NE;

    char* ws = (char*)d_ws;
    size_t off = 0;
    auto alloc = [&](size_t bytes) {
        void* p = ws + off;
        off += (bytes + 255) & ~(size_t)255;
        return p;
    };
    unsigned short* xb = (unsigned short*)alloc((size_t)NN * 32 * 2);
    unsigned short* hA = (unsigned short*)alloc((size_t)NN * HID * 2);  // layer0 out; reused as h2
    unsigned short* hB = (unsigned short*)alloc((size_t)NN * HID * 2);  // layer1 out
    unsigned short* a1 = (unsigned short*)alloc((size_t)NN * HID * 2);
    unsigned short* a2 = (unsigned short*)alloc((size_t)NN * HID * 2);
    unsigned short* wpk = (unsigned short*)alloc((size_t)57344 * 2);
    int* degI    = (int*)alloc(NN * sizeof(int));
    int* row_ptr = (int*)alloc(NN * sizeof(int));
    int* rowtmp  = (int*)alloc(NN * sizeof(int));
    int* cursor  = (int*)alloc(NN * sizeof(int));
    int* blockSum= (int*)alloc(512 * sizeof(int));
    int* blockOff= (int*)alloc(512 * sizeof(int));
    int* csr_src = (int*)alloc((size_t)NE * sizeof(int));
    // meanv aliases [a1|a2] (25.6MB): all mean reads complete before pred_gemm writes a1/a2
    float* meanv = (float*)a1;
    float* out = (float*)d_out;

    const int BS = 256;
    dim3 blkE((NE + BS - 1) / BS);
    int n4 = NN * 32 / 4;
    int gemm_blk = (NN / 16 + 3) / 4;   // 1563

    // ---- x -> bf16 + CSR build + weight prep ----
    hipMemsetAsync(degI, 0, NN * sizeof(int), stream);
    xcast<<<(n4 + BS - 1) / BS, BS, 0, stream>>>(x, xb, n4);
    count_kernel<<<blkE, BS, 0, stream>>>(dst, degI, NE);
    scan1_kernel<<<NBLK, SCAN_BS, 0, stream>>>(degI, rowtmp, blockSum);
    scan2_kernel<<<1, 512, 0, stream>>>(blockSum, blockOff, NBLK);
    scan3_kernel<<<NBLK, SCAN_BS, 0, stream>>>(rowtmp, blockOff, row_ptr, cursor);
    fill_kernel<<<blkE, BS, 0, stream>>>(src, dst, cursor, csr_src, NE);
    wprep<<<14, 256, 0, stream>>>(Wl0, Wr0, Wl1, Wr1, Wl2, Wr2, W1, wpk);

    // ---- layer 0 ----
    aggregate<32><<<NN / 4, 256, 0, stream>>>(row_ptr, degI, csr_src, xb, meanv);
    sage_gemm<32, true><<<gemm_blk, 256, 0, stream>>>(meanv, xb, wpk + 0, wpk + 4096, bl0, hA);
    // ---- layer 1 ----
    aggregate<64><<<NN / 4, 256, 0, stream>>>(row_ptr, degI, csr_src, hA, meanv);
    sage_gemm<64, true><<<gemm_blk, 256, 0, stream>>>(meanv, hA, wpk + 8192, wpk + 16384, bl1, hB);
    // ---- layer 2 (no ReLU) ----
    aggregate<64><<<NN / 4, 256, 0, stream>>>(row_ptr, degI, csr_src, hB, meanv);
    sage_gemm<64, false><<<gemm_blk, 256, 0, stream>>>(meanv, hB, wpk + 24576, wpk + 32768, bl2, hA);
    // ---- a1/a2 = h2 @ W1 halves ----
    pred_gemm<<<gemm_blk, 256, 0, stream>>>(hA, wpk + 40960, wpk + 49152, a1, a2);

    // ---- edge predictor (VALU, one edge per lane, packed f32) ----
    edge_pred<<<blkE, BS, 0, stream>>>(src, dst, a1, a2, ea, W1, b1, W2, b2, W3, b3, out, NE);
}

// Round 7
// 587.012 us; speedup vs baseline: 1.0680x; 1.0680x over previous
//
#include <hip/hip_runtime.h>
#include <hip/hip_bf16.h>

#define NN 100000
#define NE 1600000
#define HID 64
#define SCAN_BS 256
#define NBLK ((NN + SCAN_BS - 1) / SCAN_BS)   // 391

typedef float f32x4 __attribute__((ext_vector_type(4)));
typedef short bf16x8 __attribute__((ext_vector_type(8)));

__device__ __forceinline__ float bflo(unsigned u) { return __uint_as_float(u << 16); }
__device__ __forceinline__ float bfhi(unsigned u) { return __uint_as_float(u & 0xffff0000u); }
__device__ __forceinline__ unsigned short f2bf(float f) {
    __hip_bfloat16 h = (__hip_bfloat16)f;
    return *(unsigned short*)&h;
}

// ---------- x -> bf16 ----------
__global__ void xcast(const float* __restrict__ in, unsigned short* __restrict__ out, int n4) {
    int i = blockIdx.x * blockDim.x + threadIdx.x;
    if (i >= n4) return;
    float4 v = ((const float4*)in)[i];
    ushort4 o;
    o.x = f2bf(v.x); o.y = f2bf(v.y); o.z = f2bf(v.z); o.w = f2bf(v.w);
    ((ushort4*)out)[i] = o;
}

// ---------- CSR build ----------
__global__ void count_kernel(const int* __restrict__ dst, int* __restrict__ degI, int nE) {
    int e = blockIdx.x * blockDim.x + threadIdx.x;
    if (e < nE) atomicAdd(&degI[dst[e]], 1);
}

__global__ void scan1_kernel(const int* __restrict__ degI, int* __restrict__ rowtmp,
                             int* __restrict__ blockSum) {
    __shared__ int tmp[SCAN_BS];
    int t = threadIdx.x;
    int i = blockIdx.x * SCAN_BS + t;
    int d = (i < NN) ? degI[i] : 0;
    tmp[t] = d;
    __syncthreads();
    for (int off = 1; off < SCAN_BS; off <<= 1) {
        int v = (t >= off) ? tmp[t - off] : 0;
        __syncthreads();
        tmp[t] += v;
        __syncthreads();
    }
    if (i < NN) rowtmp[i] = tmp[t] - d;
    if (t == SCAN_BS - 1) blockSum[blockIdx.x] = tmp[t];
}

__global__ void scan2_kernel(const int* __restrict__ blockSum, int* __restrict__ blockOff, int n) {
    __shared__ int tmp[512];
    int t = threadIdx.x;
    tmp[t] = (t < n) ? blockSum[t] : 0;
    __syncthreads();
    for (int off = 1; off < 512; off <<= 1) {
        int v = (t >= off) ? tmp[t - off] : 0;
        __syncthreads();
        tmp[t] += v;
        __syncthreads();
    }
    if (t < n) blockOff[t] = (t == 0) ? 0 : tmp[t - 1];
}

// also initializes cursor = row_ptr so fill_kernel needs no row_ptr read / no memset
__global__ void scan3_kernel(const int* __restrict__ rowtmp, const int* __restrict__ blockOff,
                             int* __restrict__ row_ptr, int* __restrict__ cursor) {
    int i = blockIdx.x * SCAN_BS + threadIdx.x;
    if (i < NN) {
        int v = rowtmp[i] + blockOff[blockIdx.x];
        row_ptr[i] = v;
        cursor[i] = v;
    }
}

__global__ void fill_kernel(const int* __restrict__ src, const int* __restrict__ dst,
                            int* __restrict__ cursor, int* __restrict__ csr_src, int nE) {
    int e = blockIdx.x * blockDim.x + threadIdx.x;
    if (e >= nE) return;
    int d = dst[e];
    int pos = atomicAdd(&cursor[d], 1);
    csr_src[pos] = src[e];
}

// ---------- pure gather/mean (one wave per node, 4 gathers in flight, shuffle reduce) ----------
// LPE = IN/8 lanes cover one row (uint4 = 8 bf16 = 16 B per lane).
// Main loop: 4-wide (4 independent gathers issued back-to-back).
// Tail: ONE predicated 3-wide shot (masked index load -> dummy row 0, masked accumulate)
// so the tail also has full memory-level parallelism instead of a serial loop.
// Per-lane accumulation order is increasing e in both paths -> bit-identical to the
// previous 2-wide/serial-tail version.
template <int IN>
__launch_bounds__(256)
__global__ void aggregate(const int* __restrict__ row_ptr, const int* __restrict__ degI,
                          const int* __restrict__ csr_src,
                          const unsigned short* __restrict__ hin,
                          float* __restrict__ mout) {
    constexpr int LPE = IN / 8;
    constexpr int SPLIT = 64 / LPE;
    int g = threadIdx.x >> 6;
    int lane = threadIdx.x & 63;
    int node = blockIdx.x * 4 + g;         // grid sized so node < NN always
    int lane_p = lane & (LPE - 1);
    int sub = lane / LPE;

    float acc[8];
#pragma unroll
    for (int i = 0; i < 8; ++i) acc[i] = 0.f;

    int start = row_ptr[node];
    int dg = degI[node];
    const int* cs = csr_src + start;
    const unsigned short* hp = hin + 8 * lane_p;

    int e = sub;
    for (; e + SPLIT * 3 < dg; e += SPLIT * 4) {
        int s0 = cs[e];
        int s1 = cs[e + SPLIT];
        int s2 = cs[e + SPLIT * 2];
        int s3 = cs[e + SPLIT * 3];
        uint4 u0 = *(const uint4*)(hp + (size_t)s0 * IN);
        uint4 u1 = *(const uint4*)(hp + (size_t)s1 * IN);
        uint4 u2 = *(const uint4*)(hp + (size_t)s2 * IN);
        uint4 u3 = *(const uint4*)(hp + (size_t)s3 * IN);
        acc[0] += bflo(u0.x); acc[1] += bfhi(u0.x);
        acc[2] += bflo(u0.y); acc[3] += bfhi(u0.y);
        acc[4] += bflo(u0.z); acc[5] += bfhi(u0.z);
        acc[6] += bflo(u0.w); acc[7] += bfhi(u0.w);
        acc[0] += bflo(u1.x); acc[1] += bfhi(u1.x);
        acc[2] += bflo(u1.y); acc[3] += bfhi(u1.y);
        acc[4] += bflo(u1.z); acc[5] += bfhi(u1.z);
        acc[6] += bflo(u1.w); acc[7] += bfhi(u1.w);
        acc[0] += bflo(u2.x); acc[1] += bfhi(u2.x);
        acc[2] += bflo(u2.y); acc[3] += bfhi(u2.y);
        acc[4] += bflo(u2.z); acc[5] += bfhi(u2.z);
        acc[6] += bflo(u2.w); acc[7] += bfhi(u2.w);
        acc[0] += bflo(u3.x); acc[1] += bfhi(u3.x);
        acc[2] += bflo(u3.y); acc[3] += bfhi(u3.y);
        acc[4] += bflo(u3.z); acc[5] += bfhi(u3.z);
        acc[6] += bflo(u3.w); acc[7] += bfhi(u3.w);
    }
    if (e < dg) {
        bool m1 = (e + SPLIT) < dg;
        bool m2 = (e + SPLIT * 2) < dg;
        int s0 = cs[e];
        int s1 = m1 ? cs[e + SPLIT] : s0;
        int s2 = m2 ? cs[e + SPLIT * 2] : s0;
        uint4 u0 = *(const uint4*)(hp + (size_t)s0 * IN);
        uint4 u1 = *(const uint4*)(hp + (size_t)s1 * IN);
        uint4 u2 = *(const uint4*)(hp + (size_t)s2 * IN);
        acc[0] += bflo(u0.x); acc[1] += bfhi(u0.x);
        acc[2] += bflo(u0.y); acc[3] += bfhi(u0.y);
        acc[4] += bflo(u0.z); acc[5] += bfhi(u0.z);
        acc[6] += bflo(u0.w); acc[7] += bfhi(u0.w);
        if (m1) {
            acc[0] += bflo(u1.x); acc[1] += bfhi(u1.x);
            acc[2] += bflo(u1.y); acc[3] += bfhi(u1.y);
            acc[4] += bflo(u1.z); acc[5] += bfhi(u1.z);
            acc[6] += bflo(u1.w); acc[7] += bfhi(u1.w);
        }
        if (m2) {
            acc[0] += bflo(u2.x); acc[1] += bfhi(u2.x);
            acc[2] += bflo(u2.y); acc[3] += bfhi(u2.y);
            acc[4] += bflo(u2.z); acc[5] += bfhi(u2.z);
            acc[6] += bflo(u2.w); acc[7] += bfhi(u2.w);
        }
    }

    // reduce across the SPLIT sub-groups (lanes LPE apart and up)
#pragma unroll
    for (int m = LPE; m < 64; m <<= 1) {
#pragma unroll
        for (int i = 0; i < 8; ++i) acc[i] += __shfl_xor(acc[i], m);
    }
    if (sub == 0) {
        float r = 1.0f / fmaxf((float)dg, 1.0f);
        float4 v0, v1;
        v0.x = acc[0] * r; v0.y = acc[1] * r; v0.z = acc[2] * r; v0.w = acc[3] * r;
        v1.x = acc[4] * r; v1.y = acc[5] * r; v1.z = acc[6] * r; v1.w = acc[7] * r;
        float* p = mout + (size_t)node * IN + 8 * lane_p;
        *(float4*)p = v0;
        *(float4*)(p + 4) = v1;
    }
}

// ---------- weight prep: f32 [K][64] -> packed bf16 hi/lo B-fragments ----------
__global__ void wprep(const float* __restrict__ Wl0, const float* __restrict__ Wr0,
                      const float* __restrict__ Wl1, const float* __restrict__ Wr1,
                      const float* __restrict__ Wl2, const float* __restrict__ Wr2,
                      const float* __restrict__ W1, unsigned short* __restrict__ out) {
    int b = blockIdx.x;
    int mid, local;
    if (b < 2) { mid = b; local = 0; }                  // K=32 matrices: 1 block each
    else { mid = 2 + (b - 2) / 2; local = (b - 2) & 1; } // K=64 matrices: 2 blocks each
    const float* Ws[8] = {Wl0, Wr0, Wl1, Wr1, Wl2, Wr2, W1, W1 + 64 * 64};
    const int offs[8] = {0, 4096, 8192, 16384, 24576, 32768, 40960, 49152};
    const float* W = Ws[mid];
    int e = local * 256 + threadIdx.x;   // entry = (ks*4+nt)*64 + lane
    int lane = e & 63;
    int fi = e >> 6;                     // ks*4 + nt
    int ks = fi >> 2, nt = fi & 3;
    int lg = lane >> 4, col = lane & 15;
    unsigned short hi[8], lo[8];
#pragma unroll
    for (int j = 0; j < 8; ++j) {
        float w = W[(ks * 32 + lg * 8 + j) * 64 + nt * 16 + col];
        unsigned short h = f2bf(w);
        hi[j] = h;
        lo[j] = f2bf(w - bflo(h));
    }
    unsigned short* dh = out + offs[mid] + ((size_t)(fi * 2 + 0) * 64 + lane) * 8;
    unsigned short* dl = out + offs[mid] + ((size_t)(fi * 2 + 1) * 64 + lane) * 8;
#pragma unroll
    for (int j = 0; j < 8; ++j) { dh[j] = hi[j]; dl[j] = lo[j]; }
}

// ---------- MFMA GEMM: hout = act( mean@Wl + bl + hroot@Wr ) ----------
template <int KIN, bool RELU>
__launch_bounds__(256)
__global__ void sage_gemm(const float* __restrict__ meanv,
                          const unsigned short* __restrict__ hroot,
                          const unsigned short* __restrict__ wl_pk,
                          const unsigned short* __restrict__ wr_pk,
                          const float* __restrict__ bl,
                          unsigned short* __restrict__ hout) {
    constexpr int NKS = KIN / 32;
    int wid = threadIdx.x >> 6, lane = threadIdx.x & 63;
    int tile = blockIdx.x * 4 + wid;
    if (tile >= NN / 16) return;
    int m0 = tile * 16;
    int ar = lane & 15;     // A row / D col
    int lg = lane >> 4;

    bf16x8 ah[NKS];
#pragma unroll
    for (int ks = 0; ks < NKS; ++ks)
        ah[ks] = *(const bf16x8*)(hroot + (size_t)(m0 + ar) * KIN + ks * 32 + lg * 8);

    bf16x8 amh[NKS], aml[NKS];
#pragma unroll
    for (int ks = 0; ks < NKS; ++ks) {
        const float* p = meanv + (size_t)(m0 + ar) * KIN + ks * 32 + lg * 8;
        float4 v0 = *(const float4*)p;
        float4 v1 = *(const float4*)(p + 4);
        float mv[8] = {v0.x, v0.y, v0.z, v0.w, v1.x, v1.y, v1.z, v1.w};
#pragma unroll
        for (int j = 0; j < 8; ++j) {
            unsigned short h = f2bf(mv[j]);
            amh[ks][j] = (short)h;
            aml[ks][j] = (short)f2bf(mv[j] - bflo(h));
        }
    }

#pragma unroll
    for (int nt = 0; nt < 4; ++nt) {
        f32x4 acc = {0.f, 0.f, 0.f, 0.f};
#pragma unroll
        for (int ks = 0; ks < NKS; ++ks) {
            int fi = ks * 4 + nt;
            bf16x8 wlh = *(const bf16x8*)(wl_pk + ((size_t)(fi * 2 + 0) * 64 + lane) * 8);
            bf16x8 wll = *(const bf16x8*)(wl_pk + ((size_t)(fi * 2 + 1) * 64 + lane) * 8);
            bf16x8 wrh = *(const bf16x8*)(wr_pk + ((size_t)(fi * 2 + 0) * 64 + lane) * 8);
            bf16x8 wrl = *(const bf16x8*)(wr_pk + ((size_t)(fi * 2 + 1) * 64 + lane) * 8);
            acc = __builtin_amdgcn_mfma_f32_16x16x32_bf16(amh[ks], wlh, acc, 0, 0, 0);
            acc = __builtin_amdgcn_mfma_f32_16x16x32_bf16(amh[ks], wll, acc, 0, 0, 0);
            acc = __builtin_amdgcn_mfma_f32_16x16x32_bf16(aml[ks], wlh, acc, 0, 0, 0);
            acc = __builtin_amdgcn_mfma_f32_16x16x32_bf16(ah[ks],  wrh, acc, 0, 0, 0);
            acc = __builtin_amdgcn_mfma_f32_16x16x32_bf16(ah[ks],  wrl, acc, 0, 0, 0);
        }
        float b = bl[nt * 16 + ar];
#pragma unroll
        for (int r = 0; r < 4; ++r) {
            float o = acc[r] + b;
            if (RELU) o = fmaxf(o, 0.f);
            hout[(size_t)(m0 + lg * 4 + r) * 64 + nt * 16 + ar] = f2bf(o);
        }
    }
}

// ---------- a1/a2 = h2 @ W1[0:64], h2 @ W1[64:128] ----------
__launch_bounds__(256)
__global__ void pred_gemm(const unsigned short* __restrict__ h2,
                          const unsigned short* __restrict__ wa_pk,
                          const unsigned short* __restrict__ wb_pk,
                          unsigned short* __restrict__ a1,
                          unsigned short* __restrict__ a2) {
    int wid = threadIdx.x >> 6, lane = threadIdx.x & 63;
    int tile = blockIdx.x * 4 + wid;
    if (tile >= NN / 16) return;
    int m0 = tile * 16;
    int ar = lane & 15;
    int lg = lane >> 4;
    bf16x8 ah[2];
#pragma unroll
    for (int ks = 0; ks < 2; ++ks)
        ah[ks] = *(const bf16x8*)(h2 + (size_t)(m0 + ar) * 64 + ks * 32 + lg * 8);
#pragma unroll
    for (int nt = 0; nt < 4; ++nt) {
        f32x4 p = {0.f, 0.f, 0.f, 0.f};
        f32x4 q = {0.f, 0.f, 0.f, 0.f};
#pragma unroll
        for (int ks = 0; ks < 2; ++ks) {
            int fi = ks * 4 + nt;
            bf16x8 wah = *(const bf16x8*)(wa_pk + ((size_t)(fi * 2 + 0) * 64 + lane) * 8);
            bf16x8 wal = *(const bf16x8*)(wa_pk + ((size_t)(fi * 2 + 1) * 64 + lane) * 8);
            bf16x8 wbh = *(const bf16x8*)(wb_pk + ((size_t)(fi * 2 + 0) * 64 + lane) * 8);
            bf16x8 wbl = *(const bf16x8*)(wb_pk + ((size_t)(fi * 2 + 1) * 64 + lane) * 8);
            p = __builtin_amdgcn_mfma_f32_16x16x32_bf16(ah[ks], wah, p, 0, 0, 0);
            p = __builtin_amdgcn_mfma_f32_16x16x32_bf16(ah[ks], wal, p, 0, 0, 0);
            q = __builtin_amdgcn_mfma_f32_16x16x32_bf16(ah[ks], wbh, q, 0, 0, 0);
            q = __builtin_amdgcn_mfma_f32_16x16x32_bf16(ah[ks], wbl, q, 0, 0, 0);
        }
#pragma unroll
        for (int r = 0; r < 4; ++r) {
            size_t off = (size_t)(m0 + lg * 4 + r) * 64 + nt * 16 + ar;
            a1[off] = f2bf(p[r]);
            a2[off] = f2bf(q[r]);
        }
    }
}

// ---------- edge predictor (R4-proven scalar VALU version: one edge per lane) ----------
__launch_bounds__(256)
__global__ void edge_pred(const int* __restrict__ src, const int* __restrict__ dst,
                          const unsigned short* __restrict__ a1, const unsigned short* __restrict__ a2,
                          const float* __restrict__ ea,
                          const float* __restrict__ W1, const float* __restrict__ b1,
                          const float* __restrict__ W2, const float* __restrict__ b2,
                          const float* __restrict__ W3, const float* __restrict__ b3,
                          float* __restrict__ out, int nE) {
    int e = blockIdx.x * blockDim.x + threadIdx.x;
    if (e >= nE) return;
    int s = src[e];
    int d = dst[e];

    const uint4* pa = (const uint4*)(a1 + (size_t)s * 64);
    const uint4* pb = (const uint4*)(a2 + (size_t)d * 64);
    const float4* eav = (const float4*)(ea + (size_t)e * 8);
    float4 v0 = eav[0];
    float4 v1 = eav[1];

    float z1[64];
    const float* wr = W1 + 128 * 64;
#pragma unroll
    for (int j = 0; j < 64; ++j) {
        float a = fmaf(v0.x, wr[j], b1[j]);
        a = fmaf(v0.y, wr[64 + j], a);
        a = fmaf(v0.z, wr[128 + j], a);
        a = fmaf(v0.w, wr[192 + j], a);
        a = fmaf(v1.x, wr[256 + j], a);
        a = fmaf(v1.y, wr[320 + j], a);
        a = fmaf(v1.z, wr[384 + j], a);
        z1[j] = fmaf(v1.w, wr[448 + j], a);
    }

#pragma unroll
    for (int q = 0; q < 8; ++q) {
        uint4 ua = pa[q];
        uint4 ub = pb[q];
        int j0 = q * 8;
        z1[j0 + 0] += bflo(ua.x) + bflo(ub.x);
        z1[j0 + 1] += bfhi(ua.x) + bfhi(ub.x);
        z1[j0 + 2] += bflo(ua.y) + bflo(ub.y);
        z1[j0 + 3] += bfhi(ua.y) + bfhi(ub.y);
        z1[j0 + 4] += bflo(ua.z) + bflo(ub.z);
        z1[j0 + 5] += bfhi(ua.z) + bfhi(ub.z);
        z1[j0 + 6] += bflo(ua.w) + bflo(ub.w);
        z1[j0 + 7] += bfhi(ua.w) + bfhi(ub.w);
    }

    float z2[32];
#pragma unroll
    for (int j = 0; j < 32; ++j) z2[j] = b2[j];
    for (int k = 0; k < 64; ++k) {
        float v = fmaxf(z1[k], 0.0f);
        const float* w = W2 + (size_t)k * 32;
#pragma unroll
        for (int j = 0; j < 32; ++j) z2[j] = fmaf(v, w[j], z2[j]);
    }

    float o = b3[0];
#pragma unroll
    for (int k = 0; k < 32; ++k) o = fmaf(fmaxf(z2[k], 0.0f), W3[k], o);

    out[e] = 1.0f / (1.0f + __expf(-o));
}

extern "C" void kernel_launch(void* const* d_in, const int* in_sizes, int n_in,
                              void* d_out, int out_size, void* d_ws, size_t ws_size,
                              hipStream_t stream) {
    const float* x   = (const float*)d_in[0];
    const int*   ei  = (const int*)d_in[1];
    const float* ea  = (const float*)d_in[2];
    const float* Wl0 = (const float*)d_in[3];
    const float* bl0 = (const float*)d_in[4];
    const float* Wr0 = (const float*)d_in[5];
    const float* Wl1 = (const float*)d_in[6];
    const float* bl1 = (const float*)d_in[7];
    const float* Wr1 = (const float*)d_in[8];
    const float* Wl2 = (const float*)d_in[9];
    const float* bl2 = (const float*)d_in[10];
    const float* Wr2 = (const float*)d_in[11];
    const float* W1  = (const float*)d_in[12];
    const float* b1  = (const float*)d_in[13];
    const float* W2  = (const float*)d_in[14];
    const float* b2  = (const float*)d_in[15];
    const float* W3  = (const float*)d_in[16];
    const float* b3  = (const float*)d_in[17];

    const int* src = ei;
    const int* dst = ei + NE;

    char* ws = (char*)d_ws;
    size_t off = 0;
    auto alloc = [&](size_t bytes) {
        void* p = ws + off;
        off += (bytes + 255) & ~(size_t)255;
        return p;
    };
    unsigned short* xb = (unsigned short*)alloc((size_t)NN * 32 * 2);
    unsigned short* hA = (unsigned short*)alloc((size_t)NN * HID * 2);  // layer0 out; reused as h2
    unsigned short* hB = (unsigned short*)alloc((size_t)NN * HID * 2);  // layer1 out
    unsigned short* a1 = (unsigned short*)alloc((size_t)NN * HID * 2);
    unsigned short* a2 = (unsigned short*)alloc((size_t)NN * HID * 2);
    unsigned short* wpk = (unsigned short*)alloc((size_t)57344 * 2);
    int* degI    = (int*)alloc(NN * sizeof(int));
    int* row_ptr = (int*)alloc(NN * sizeof(int));
    int* rowtmp  = (int*)alloc(NN * sizeof(int));
    int* cursor  = (int*)alloc(NN * sizeof(int));
    int* blockSum= (int*)alloc(512 * sizeof(int));
    int* blockOff= (int*)alloc(512 * sizeof(int));
    int* csr_src = (int*)alloc((size_t)NE * sizeof(int));
    // meanv aliases [a1|a2] (25.6MB): all mean reads complete before pred_gemm writes a1/a2
    float* meanv = (float*)a1;
    float* out = (float*)d_out;

    const int BS = 256;
    dim3 blkE((NE + BS - 1) / BS);
    int n4 = NN * 32 / 4;
    int gemm_blk = (NN / 16 + 3) / 4;   // 1563

    // ---- x -> bf16 + CSR build + weight prep ----
    hipMemsetAsync(degI, 0, NN * sizeof(int), stream);
    xcast<<<(n4 + BS - 1) / BS, BS, 0, stream>>>(x, xb, n4);
    count_kernel<<<blkE, BS, 0, stream>>>(dst, degI, NE);
    scan1_kernel<<<NBLK, SCAN_BS, 0, stream>>>(degI, rowtmp, blockSum);
    scan2_kernel<<<1, 512, 0, stream>>>(blockSum, blockOff, NBLK);
    scan3_kernel<<<NBLK, SCAN_BS, 0, stream>>>(rowtmp, blockOff, row_ptr, cursor);
    fill_kernel<<<blkE, BS, 0, stream>>>(src, dst, cursor, csr_src, NE);
    wprep<<<14, 256, 0, stream>>>(Wl0, Wr0, Wl1, Wr1, Wl2, Wr2, W1, wpk);

    // ---- layer 0 ----
    aggregate<32><<<NN / 4, 256, 0, stream>>>(row_ptr, degI, csr_src, xb, meanv);
    sage_gemm<32, true><<<gemm_blk, 256, 0, stream>>>(meanv, xb, wpk + 0, wpk + 4096, bl0, hA);
    // ---- layer 1 ----
    aggregate<64><<<NN / 4, 256, 0, stream>>>(row_ptr, degI, csr_src, hA, meanv);
    sage_gemm<64, true><<<gemm_blk, 256, 0, stream>>>(meanv, hA, wpk + 8192, wpk + 16384, bl1, hB);
    // ---- layer 2 (no ReLU) ----
    aggregate<64><<<NN / 4, 256, 0, stream>>>(row_ptr, degI, csr_src, hB, meanv);
    sage_gemm<64, false><<<gemm_blk, 256, 0, stream>>>(meanv, hB, wpk + 24576, wpk + 32768, bl2, hA);
    // ---- a1/a2 = h2 @ W1 halves ----
    pred_gemm<<<gemm_blk, 256, 0, stream>>>(hA, wpk + 40960, wpk + 49152, a1, a2);

    // ---- edge predictor (VALU, one edge per lane) ----
    edge_pred<<<blkE, BS, 0, stream>>>(src, dst, a1, a2, ea, W1, b1, W2, b2, W3, b3, out, NE);
}

// Round 8
// 561.020 us; speedup vs baseline: 1.1174x; 1.0463x over previous
//
#include <hip/hip_runtime.h>
#include <hip/hip_bf16.h>

#define NN 100000
#define NE 1600000
#define HID 64
#define SCAN_BS 256
#define NBLK ((NN + SCAN_BS - 1) / SCAN_BS)   // 391
#define FPASS 4
#define FCHUNK ((NE + 255) / 256)             // 6250

typedef float f32x4 __attribute__((ext_vector_type(4)));
typedef short bf16x8 __attribute__((ext_vector_type(8)));

__device__ __forceinline__ float bflo(unsigned u) { return __uint_as_float(u << 16); }
__device__ __forceinline__ float bfhi(unsigned u) { return __uint_as_float(u & 0xffff0000u); }
__device__ __forceinline__ unsigned short f2bf(float f) {
    __hip_bfloat16 h = (__hip_bfloat16)f;
    return *(unsigned short*)&h;
}

// ---------- x -> bf16 ----------
__global__ void xcast(const float* __restrict__ in, unsigned short* __restrict__ out, int n4) {
    int i = blockIdx.x * blockDim.x + threadIdx.x;
    if (i >= n4) return;
    float4 v = ((const float4*)in)[i];
    ushort4 o;
    o.x = f2bf(v.x); o.y = f2bf(v.y); o.z = f2bf(v.z); o.w = f2bf(v.w);
    ((ushort4*)out)[i] = o;
}

// ---------- CSR build ----------
__global__ void count_kernel(const int* __restrict__ dst, int* __restrict__ degI, int nE) {
    int e = blockIdx.x * blockDim.x + threadIdx.x;
    if (e < nE) atomicAdd(&degI[dst[e]], 1);
}

__global__ void scan1_kernel(const int* __restrict__ degI, int* __restrict__ rowtmp,
                             int* __restrict__ blockSum) {
    __shared__ int tmp[SCAN_BS];
    int t = threadIdx.x;
    int i = blockIdx.x * SCAN_BS + t;
    int d = (i < NN) ? degI[i] : 0;
    tmp[t] = d;
    __syncthreads();
    for (int off = 1; off < SCAN_BS; off <<= 1) {
        int v = (t >= off) ? tmp[t - off] : 0;
        __syncthreads();
        tmp[t] += v;
        __syncthreads();
    }
    if (i < NN) rowtmp[i] = tmp[t] - d;
    if (t == SCAN_BS - 1) blockSum[blockIdx.x] = tmp[t];
}

__global__ void scan2_kernel(const int* __restrict__ blockSum, int* __restrict__ blockOff, int n) {
    __shared__ int tmp[512];
    int t = threadIdx.x;
    tmp[t] = (t < n) ? blockSum[t] : 0;
    __syncthreads();
    for (int off = 1; off < 512; off <<= 1) {
        int v = (t >= off) ? tmp[t - off] : 0;
        __syncthreads();
        tmp[t] += v;
        __syncthreads();
    }
    if (t < n) blockOff[t] = (t == 0) ? 0 : tmp[t - 1];
}

// also initializes cursor = row_ptr so fill_kernel needs no row_ptr read / no memset
__global__ void scan3_kernel(const int* __restrict__ rowtmp, const int* __restrict__ blockOff,
                             int* __restrict__ row_ptr, int* __restrict__ cursor) {
    int i = blockIdx.x * SCAN_BS + threadIdx.x;
    if (i < NN) {
        int v = rowtmp[i] + blockOff[blockIdx.x];
        row_ptr[i] = v;
        cursor[i] = v;
    }
}

// range-split fill: pass p handles dst in [p*25000, (p+1)*25000).
// Active write window per pass = 1.6MB csr + 100KB cursor -> fits in each XCD L2,
// so 64B lines accumulate all their 4B writes before eviction (write traffic ~6.5MB
// instead of ~105MB). Block order is pass-major (low blockIdx = pass 0).
__global__ void fill_kernel(const int* __restrict__ src, const int* __restrict__ dst,
                            int* __restrict__ cursor, int* __restrict__ csr_src, int nE) {
    int pass = blockIdx.x / FCHUNK;
    int chunk = blockIdx.x - pass * FCHUNK;
    int e = chunk * 256 + threadIdx.x;
    if (e >= nE) return;
    int d = dst[e];
    int lo = pass * (NN / FPASS);
    if (d >= lo && d < lo + (NN / FPASS)) {
        int pos = atomicAdd(&cursor[d], 1);
        csr_src[pos] = src[e];
    }
}

// ---------- pure gather/mean (one wave per node, uint4 loads, shuffle reduce) ----------
// R4-proven form: LPE = IN/8 lanes cover one row (uint4 = 8 bf16 = 16 B per lane).
// IN=64: SPLIT=8 edges in flight, UN=2 -> 16 edges per main iter (= avg degree).
// IN=32: SPLIT=16, UN=1 -> 16 edges per iter.
template <int IN>
__launch_bounds__(256)
__global__ void aggregate(const int* __restrict__ row_ptr, const int* __restrict__ degI,
                          const int* __restrict__ csr_src,
                          const unsigned short* __restrict__ hin,
                          float* __restrict__ mout) {
    constexpr int LPE = IN / 8;
    constexpr int SPLIT = 64 / LPE;
    constexpr int UN = (IN == 64) ? 2 : 1;
    int g = threadIdx.x >> 6;
    int lane = threadIdx.x & 63;
    int node = blockIdx.x * 4 + g;         // grid sized so node < NN always
    int lane_p = lane & (LPE - 1);
    int sub = lane / LPE;

    float acc[8];
#pragma unroll
    for (int i = 0; i < 8; ++i) acc[i] = 0.f;

    int start = row_ptr[node];
    int dg = degI[node];
    const int* cs = csr_src + start;

    int e = sub;
    for (; e + SPLIT * (UN - 1) < dg; e += SPLIT * UN) {
        uint4 u[UN];
#pragma unroll
        for (int j = 0; j < UN; ++j) {
            int s = cs[e + SPLIT * j];
            u[j] = *(const uint4*)(hin + (size_t)s * IN + 8 * lane_p);
        }
#pragma unroll
        for (int j = 0; j < UN; ++j) {
            acc[0] += bflo(u[j].x); acc[1] += bfhi(u[j].x);
            acc[2] += bflo(u[j].y); acc[3] += bfhi(u[j].y);
            acc[4] += bflo(u[j].z); acc[5] += bfhi(u[j].z);
            acc[6] += bflo(u[j].w); acc[7] += bfhi(u[j].w);
        }
    }
    for (; e < dg; e += SPLIT) {
        int s = cs[e];
        uint4 u = *(const uint4*)(hin + (size_t)s * IN + 8 * lane_p);
        acc[0] += bflo(u.x); acc[1] += bfhi(u.x);
        acc[2] += bflo(u.y); acc[3] += bfhi(u.y);
        acc[4] += bflo(u.z); acc[5] += bfhi(u.z);
        acc[6] += bflo(u.w); acc[7] += bfhi(u.w);
    }

    // reduce across the SPLIT sub-groups (lanes LPE apart and up)
#pragma unroll
    for (int m = LPE; m < 64; m <<= 1) {
#pragma unroll
        for (int i = 0; i < 8; ++i) acc[i] += __shfl_xor(acc[i], m);
    }
    if (sub == 0) {
        float r = 1.0f / fmaxf((float)dg, 1.0f);
        float4 v0, v1;
        v0.x = acc[0] * r; v0.y = acc[1] * r; v0.z = acc[2] * r; v0.w = acc[3] * r;
        v1.x = acc[4] * r; v1.y = acc[5] * r; v1.z = acc[6] * r; v1.w = acc[7] * r;
        float* p = mout + (size_t)node * IN + 8 * lane_p;
        *(float4*)p = v0;
        *(float4*)(p + 4) = v1;
    }
}

// ---------- weight prep: f32 [K][64] -> packed bf16 hi/lo B-fragments ----------
__global__ void wprep(const float* __restrict__ Wl0, const float* __restrict__ Wr0,
                      const float* __restrict__ Wl1, const float* __restrict__ Wr1,
                      const float* __restrict__ Wl2, const float* __restrict__ Wr2,
                      const float* __restrict__ W1, unsigned short* __restrict__ out) {
    int b = blockIdx.x;
    int mid, local;
    if (b < 2) { mid = b; local = 0; }                  // K=32 matrices: 1 block each
    else { mid = 2 + (b - 2) / 2; local = (b - 2) & 1; } // K=64 matrices: 2 blocks each
    const float* Ws[8] = {Wl0, Wr0, Wl1, Wr1, Wl2, Wr2, W1, W1 + 64 * 64};
    const int offs[8] = {0, 4096, 8192, 16384, 24576, 32768, 40960, 49152};
    const float* W = Ws[mid];
    int e = local * 256 + threadIdx.x;   // entry = (ks*4+nt)*64 + lane
    int lane = e & 63;
    int fi = e >> 6;                     // ks*4 + nt
    int ks = fi >> 2, nt = fi & 3;
    int lg = lane >> 4, col = lane & 15;
    unsigned short hi[8], lo[8];
#pragma unroll
    for (int j = 0; j < 8; ++j) {
        float w = W[(ks * 32 + lg * 8 + j) * 64 + nt * 16 + col];
        unsigned short h = f2bf(w);
        hi[j] = h;
        lo[j] = f2bf(w - bflo(h));
    }
    unsigned short* dh = out + offs[mid] + ((size_t)(fi * 2 + 0) * 64 + lane) * 8;
    unsigned short* dl = out + offs[mid] + ((size_t)(fi * 2 + 1) * 64 + lane) * 8;
#pragma unroll
    for (int j = 0; j < 8; ++j) { dh[j] = hi[j]; dl[j] = lo[j]; }
}

// ---------- MFMA GEMM: hout = act( mean@Wl + bl + hroot@Wr ) ----------
template <int KIN, bool RELU>
__launch_bounds__(256)
__global__ void sage_gemm(const float* __restrict__ meanv,
                          const unsigned short* __restrict__ hroot,
                          const unsigned short* __restrict__ wl_pk,
                          const unsigned short* __restrict__ wr_pk,
                          const float* __restrict__ bl,
                          unsigned short* __restrict__ hout) {
    constexpr int NKS = KIN / 32;
    int wid = threadIdx.x >> 6, lane = threadIdx.x & 63;
    int tile = blockIdx.x * 4 + wid;
    if (tile >= NN / 16) return;
    int m0 = tile * 16;
    int ar = lane & 15;     // A row / D col
    int lg = lane >> 4;

    bf16x8 ah[NKS];
#pragma unroll
    for (int ks = 0; ks < NKS; ++ks)
        ah[ks] = *(const bf16x8*)(hroot + (size_t)(m0 + ar) * KIN + ks * 32 + lg * 8);

    bf16x8 amh[NKS], aml[NKS];
#pragma unroll
    for (int ks = 0; ks < NKS; ++ks) {
        const float* p = meanv + (size_t)(m0 + ar) * KIN + ks * 32 + lg * 8;
        float4 v0 = *(const float4*)p;
        float4 v1 = *(const float4*)(p + 4);
        float mv[8] = {v0.x, v0.y, v0.z, v0.w, v1.x, v1.y, v1.z, v1.w};
#pragma unroll
        for (int j = 0; j < 8; ++j) {
            unsigned short h = f2bf(mv[j]);
            amh[ks][j] = (short)h;
            aml[ks][j] = (short)f2bf(mv[j] - bflo(h));
        }
    }

#pragma unroll
    for (int nt = 0; nt < 4; ++nt) {
        f32x4 acc = {0.f, 0.f, 0.f, 0.f};
#pragma unroll
        for (int ks = 0; ks < NKS; ++ks) {
            int fi = ks * 4 + nt;
            bf16x8 wlh = *(const bf16x8*)(wl_pk + ((size_t)(fi * 2 + 0) * 64 + lane) * 8);
            bf16x8 wll = *(const bf16x8*)(wl_pk + ((size_t)(fi * 2 + 1) * 64 + lane) * 8);
            bf16x8 wrh = *(const bf16x8*)(wr_pk + ((size_t)(fi * 2 + 0) * 64 + lane) * 8);
            bf16x8 wrl = *(const bf16x8*)(wr_pk + ((size_t)(fi * 2 + 1) * 64 + lane) * 8);
            acc = __builtin_amdgcn_mfma_f32_16x16x32_bf16(amh[ks], wlh, acc, 0, 0, 0);
            acc = __builtin_amdgcn_mfma_f32_16x16x32_bf16(amh[ks], wll, acc, 0, 0, 0);
            acc = __builtin_amdgcn_mfma_f32_16x16x32_bf16(aml[ks], wlh, acc, 0, 0, 0);
            acc = __builtin_amdgcn_mfma_f32_16x16x32_bf16(ah[ks],  wrh, acc, 0, 0, 0);
            acc = __builtin_amdgcn_mfma_f32_16x16x32_bf16(ah[ks],  wrl, acc, 0, 0, 0);
        }
        float b = bl[nt * 16 + ar];
#pragma unroll
        for (int r = 0; r < 4; ++r) {
            float o = acc[r] + b;
            if (RELU) o = fmaxf(o, 0.f);
            hout[(size_t)(m0 + lg * 4 + r) * 64 + nt * 16 + ar] = f2bf(o);
        }
    }
}

// ---------- a1/a2 = h2 @ W1[0:64], h2 @ W1[64:128] ----------
__launch_bounds__(256)
__global__ void pred_gemm(const unsigned short* __restrict__ h2,
                          const unsigned short* __restrict__ wa_pk,
                          const unsigned short* __restrict__ wb_pk,
                          unsigned short* __restrict__ a1,
                          unsigned short* __restrict__ a2) {
    int wid = threadIdx.x >> 6, lane = threadIdx.x & 63;
    int tile = blockIdx.x * 4 + wid;
    if (tile >= NN / 16) return;
    int m0 = tile * 16;
    int ar = lane & 15;
    int lg = lane >> 4;
    bf16x8 ah[2];
#pragma unroll
    for (int ks = 0; ks < 2; ++ks)
        ah[ks] = *(const bf16x8*)(h2 + (size_t)(m0 + ar) * 64 + ks * 32 + lg * 8);
#pragma unroll
    for (int nt = 0; nt < 4; ++nt) {
        f32x4 p = {0.f, 0.f, 0.f, 0.f};
        f32x4 q = {0.f, 0.f, 0.f, 0.f};
#pragma unroll
        for (int ks = 0; ks < 2; ++ks) {
            int fi = ks * 4 + nt;
            bf16x8 wah = *(const bf16x8*)(wa_pk + ((size_t)(fi * 2 + 0) * 64 + lane) * 8);
            bf16x8 wal = *(const bf16x8*)(wa_pk + ((size_t)(fi * 2 + 1) * 64 + lane) * 8);
            bf16x8 wbh = *(const bf16x8*)(wb_pk + ((size_t)(fi * 2 + 0) * 64 + lane) * 8);
            bf16x8 wbl = *(const bf16x8*)(wb_pk + ((size_t)(fi * 2 + 1) * 64 + lane) * 8);
            p = __builtin_amdgcn_mfma_f32_16x16x32_bf16(ah[ks], wah, p, 0, 0, 0);
            p = __builtin_amdgcn_mfma_f32_16x16x32_bf16(ah[ks], wal, p, 0, 0, 0);
            q = __builtin_amdgcn_mfma_f32_16x16x32_bf16(ah[ks], wbh, q, 0, 0, 0);
            q = __builtin_amdgcn_mfma_f32_16x16x32_bf16(ah[ks], wbl, q, 0, 0, 0);
        }
#pragma unroll
        for (int r = 0; r < 4; ++r) {
            size_t off = (size_t)(m0 + lg * 4 + r) * 64 + nt * 16 + ar;
            a1[off] = f2bf(p[r]);
            a2[off] = f2bf(q[r]);
        }
    }
}

// ---------- edge predictor (R4-proven scalar VALU version: one edge per lane) ----------
__launch_bounds__(256)
__global__ void edge_pred(const int* __restrict__ src, const int* __restrict__ dst,
                          const unsigned short* __restrict__ a1, const unsigned short* __restrict__ a2,
                          const float* __restrict__ ea,
                          const float* __restrict__ W1, const float* __restrict__ b1,
                          const float* __restrict__ W2, const float* __restrict__ b2,
                          const float* __restrict__ W3, const float* __restrict__ b3,
                          float* __restrict__ out, int nE) {
    int e = blockIdx.x * blockDim.x + threadIdx.x;
    if (e >= nE) return;
    int s = src[e];
    int d = dst[e];

    const uint4* pa = (const uint4*)(a1 + (size_t)s * 64);
    const uint4* pb = (const uint4*)(a2 + (size_t)d * 64);
    const float4* eav = (const float4*)(ea + (size_t)e * 8);
    float4 v0 = eav[0];
    float4 v1 = eav[1];

    float z1[64];
    const float* wr = W1 + 128 * 64;
#pragma unroll
    for (int j = 0; j < 64; ++j) {
        float a = fmaf(v0.x, wr[j], b1[j]);
        a = fmaf(v0.y, wr[64 + j], a);
        a = fmaf(v0.z, wr[128 + j], a);
        a = fmaf(v0.w, wr[192 + j], a);
        a = fmaf(v1.x, wr[256 + j], a);
        a = fmaf(v1.y, wr[320 + j], a);
        a = fmaf(v1.z, wr[384 + j], a);
        z1[j] = fmaf(v1.w, wr[448 + j], a);
    }

#pragma unroll
    for (int q = 0; q < 8; ++q) {
        uint4 ua = pa[q];
        uint4 ub = pb[q];
        int j0 = q * 8;
        z1[j0 + 0] += bflo(ua.x) + bflo(ub.x);
        z1[j0 + 1] += bfhi(ua.x) + bfhi(ub.x);
        z1[j0 + 2] += bflo(ua.y) + bflo(ub.y);
        z1[j0 + 3] += bfhi(ua.y) + bfhi(ub.y);
        z1[j0 + 4] += bflo(ua.z) + bflo(ub.z);
        z1[j0 + 5] += bfhi(ua.z) + bfhi(ub.z);
        z1[j0 + 6] += bflo(ua.w) + bflo(ub.w);
        z1[j0 + 7] += bfhi(ua.w) + bfhi(ub.w);
    }

    float z2[32];
#pragma unroll
    for (int j = 0; j < 32; ++j) z2[j] = b2[j];
    for (int k = 0; k < 64; ++k) {
        float v = fmaxf(z1[k], 0.0f);
        const float* w = W2 + (size_t)k * 32;
#pragma unroll
        for (int j = 0; j < 32; ++j) z2[j] = fmaf(v, w[j], z2[j]);
    }

    float o = b3[0];
#pragma unroll
    for (int k = 0; k < 32; ++k) o = fmaf(fmaxf(z2[k], 0.0f), W3[k], o);

    out[e] = 1.0f / (1.0f + __expf(-o));
}

extern "C" void kernel_launch(void* const* d_in, const int* in_sizes, int n_in,
                              void* d_out, int out_size, void* d_ws, size_t ws_size,
                              hipStream_t stream) {
    const float* x   = (const float*)d_in[0];
    const int*   ei  = (const int*)d_in[1];
    const float* ea  = (const float*)d_in[2];
    const float* Wl0 = (const float*)d_in[3];
    const float* bl0 = (const float*)d_in[4];
    const float* Wr0 = (const float*)d_in[5];
    const float* Wl1 = (const float*)d_in[6];
    const float* bl1 = (const float*)d_in[7];
    const float* Wr1 = (const float*)d_in[8];
    const float* Wl2 = (const float*)d_in[9];
    const float* bl2 = (const float*)d_in[10];
    const float* Wr2 = (const float*)d_in[11];
    const float* W1  = (const float*)d_in[12];
    const float* b1  = (const float*)d_in[13];
    const float* W2  = (const float*)d_in[14];
    const float* b2  = (const float*)d_in[15];
    const float* W3  = (const float*)d_in[16];
    const float* b3  = (const float*)d_in[17];

    const int* src = ei;
    const int* dst = ei + NE;

    char* ws = (char*)d_ws;
    size_t off = 0;
    auto alloc = [&](size_t bytes) {
        void* p = ws + off;
        off += (bytes + 255) & ~(size_t)255;
        return p;
    };
    unsigned short* xb = (unsigned short*)alloc((size_t)NN * 32 * 2);
    unsigned short* hA = (unsigned short*)alloc((size_t)NN * HID * 2);  // layer0 out; reused as h2
    unsigned short* hB = (unsigned short*)alloc((size_t)NN * HID * 2);  // layer1 out
    unsigned short* a1 = (unsigned short*)alloc((size_t)NN * HID * 2);
    unsigned short* a2 = (unsigned short*)alloc((size_t)NN * HID * 2);
    unsigned short* wpk = (unsigned short*)alloc((size_t)57344 * 2);
    int* degI    = (int*)alloc(NN * sizeof(int));
    int* row_ptr = (int*)alloc(NN * sizeof(int));
    int* rowtmp  = (int*)alloc(NN * sizeof(int));
    int* cursor  = (int*)alloc(NN * sizeof(int));
    int* blockSum= (int*)alloc(512 * sizeof(int));
    int* blockOff= (int*)alloc(512 * sizeof(int));
    int* csr_src = (int*)alloc((size_t)NE * sizeof(int));
    // meanv aliases [a1|a2] (25.6MB): all mean reads complete before pred_gemm writes a1/a2
    float* meanv = (float*)a1;
    float* out = (float*)d_out;

    const int BS = 256;
    dim3 blkE((NE + BS - 1) / BS);
    int n4 = NN * 32 / 4;
    int gemm_blk = (NN / 16 + 3) / 4;   // 1563

    // ---- x -> bf16 + CSR build + weight prep ----
    hipMemsetAsync(degI, 0, NN * sizeof(int), stream);
    xcast<<<(n4 + BS - 1) / BS, BS, 0, stream>>>(x, xb, n4);
    count_kernel<<<blkE, BS, 0, stream>>>(dst, degI, NE);
    scan1_kernel<<<NBLK, SCAN_BS, 0, stream>>>(degI, rowtmp, blockSum);
    scan2_kernel<<<1, 512, 0, stream>>>(blockSum, blockOff, NBLK);
    scan3_kernel<<<NBLK, SCAN_BS, 0, stream>>>(rowtmp, blockOff, row_ptr, cursor);
    fill_kernel<<<FPASS * FCHUNK, BS, 0, stream>>>(src, dst, cursor, csr_src, NE);
    wprep<<<14, 256, 0, stream>>>(Wl0, Wr0, Wl1, Wr1, Wl2, Wr2, W1, wpk);

    // ---- layer 0 ----
    aggregate<32><<<NN / 4, 256, 0, stream>>>(row_ptr, degI, csr_src, xb, meanv);
    sage_gemm<32, true><<<gemm_blk, 256, 0, stream>>>(meanv, xb, wpk + 0, wpk + 4096, bl0, hA);
    // ---- layer 1 ----
    aggregate<64><<<NN / 4, 256, 0, stream>>>(row_ptr, degI, csr_src, hA, meanv);
    sage_gemm<64, true><<<gemm_blk, 256, 0, stream>>>(meanv, hA, wpk + 8192, wpk + 16384, bl1, hB);
    // ---- layer 2 (no ReLU) ----
    aggregate<64><<<NN / 4, 256, 0, stream>>>(row_ptr, degI, csr_src, hB, meanv);
    sage_gemm<64, false><<<gemm_blk, 256, 0, stream>>>(meanv, hB, wpk + 24576, wpk + 32768, bl2, hA);
    // ---- a1/a2 = h2 @ W1 halves ----
    pred_gemm<<<gemm_blk, 256, 0, stream>>>(hA, wpk + 40960, wpk + 49152, a1, a2);

    // ---- edge predictor (VALU, one edge per lane) ----
    edge_pred<<<blkE, BS, 0, stream>>>(src, dst, a1, a2, ea, W1, b1, W2, b2, W3, b3, out, NE);
}

// Round 9
// 533.814 us; speedup vs baseline: 1.1744x; 1.0510x over previous
//
#include <hip/hip_runtime.h>
#include <hip/hip_bf16.h>

#define NN 100000
#define NE 1600000
#define HID 64
#define SCAN_BS 256
#define NBLK ((NN + SCAN_BS - 1) / SCAN_BS)   // 391
#define NSLICE 8
#define SLICEN (NN / NSLICE)                  // 12500
#define FCHUNK ((NE + 255) / 256)             // 6250

typedef float f32x4 __attribute__((ext_vector_type(4)));
typedef short bf16x8 __attribute__((ext_vector_type(8)));

__device__ __forceinline__ float bflo(unsigned u) { return __uint_as_float(u << 16); }
__device__ __forceinline__ float bfhi(unsigned u) { return __uint_as_float(u & 0xffff0000u); }
__device__ __forceinline__ unsigned short f2bf(float f) {
    __hip_bfloat16 h = (__hip_bfloat16)f;
    return *(unsigned short*)&h;
}

// ---------- x -> bf16 ----------
__global__ void xcast(const float* __restrict__ in, unsigned short* __restrict__ out, int n4) {
    int i = blockIdx.x * blockDim.x + threadIdx.x;
    if (i >= n4) return;
    float4 v = ((const float4*)in)[i];
    ushort4 o;
    o.x = f2bf(v.x); o.y = f2bf(v.y); o.z = f2bf(v.z); o.w = f2bf(v.w);
    ((ushort4*)out)[i] = o;
}

// ---------- CSR build ----------
__global__ void count_kernel(const int* __restrict__ dst, int* __restrict__ degI, int nE) {
    int e = blockIdx.x * blockDim.x + threadIdx.x;
    if (e < nE) atomicAdd(&degI[dst[e]], 1);
}

__global__ void scan1_kernel(const int* __restrict__ degI, int* __restrict__ rowtmp,
                             int* __restrict__ blockSum) {
    __shared__ int tmp[SCAN_BS];
    int t = threadIdx.x;
    int i = blockIdx.x * SCAN_BS + t;
    int d = (i < NN) ? degI[i] : 0;
    tmp[t] = d;
    __syncthreads();
    for (int off = 1; off < SCAN_BS; off <<= 1) {
        int v = (t >= off) ? tmp[t - off] : 0;
        __syncthreads();
        tmp[t] += v;
        __syncthreads();
    }
    if (i < NN) rowtmp[i] = tmp[t] - d;
    if (t == SCAN_BS - 1) blockSum[blockIdx.x] = tmp[t];
}

__global__ void scan2_kernel(const int* __restrict__ blockSum, int* __restrict__ blockOff, int n) {
    __shared__ int tmp[512];
    int t = threadIdx.x;
    tmp[t] = (t < n) ? blockSum[t] : 0;
    __syncthreads();
    for (int off = 1; off < 512; off <<= 1) {
        int v = (t >= off) ? tmp[t - off] : 0;
        __syncthreads();
        tmp[t] += v;
        __syncthreads();
    }
    if (t < n) blockOff[t] = (t == 0) ? 0 : tmp[t - 1];
}

// also initializes cursor = row_ptr so fill_kernel needs no row_ptr read / no memset
__global__ void scan3_kernel(const int* __restrict__ rowtmp, const int* __restrict__ blockOff,
                             int* __restrict__ row_ptr, int* __restrict__ cursor) {
    int i = blockIdx.x * SCAN_BS + threadIdx.x;
    if (i < NN) {
        int v = rowtmp[i] + blockOff[blockIdx.x];
        row_ptr[i] = v;
        cursor[i] = v;
    }
}

// XCD-sliced fill: slice ownership = blockIdx % 8, which round-robins across the
// 8 XCDs on MI355X -> each csr/cursor slice (~850 KB) is written by exactly ONE
// XCD's L2. No cross-XCD line sharing, working set << 4 MB L2, so each 64B line
// absorbs all its 4B writes before a single eviction (write traffic ~13 MB
// instead of ~105 MB). Cost: dst stream read 8x (coalesced, ~8 us).
__global__ void fill_kernel(const int* __restrict__ src, const int* __restrict__ dst,
                            int* __restrict__ cursor, int* __restrict__ csr_src, int nE) {
    int slice = blockIdx.x & (NSLICE - 1);
    int chunk = blockIdx.x >> 3;
    int e = chunk * 256 + threadIdx.x;
    if (e >= nE) return;
    int d = dst[e];
    int lo = slice * SLICEN;
    if (d >= lo && d < lo + SLICEN) {
        int pos = atomicAdd(&cursor[d], 1);
        csr_src[pos] = src[e];
    }
}

// ---------- pure gather/mean (one wave per node, uint4 loads, shuffle reduce) ----------
// R4-proven form: LPE = IN/8 lanes cover one row (uint4 = 8 bf16 = 16 B per lane).
// IN=64: SPLIT=8 edges in flight, UN=2 -> 16 edges per main iter (= avg degree).
// IN=32: SPLIT=16, UN=1 -> 16 edges per iter.
template <int IN>
__launch_bounds__(256)
__global__ void aggregate(const int* __restrict__ row_ptr, const int* __restrict__ degI,
                          const int* __restrict__ csr_src,
                          const unsigned short* __restrict__ hin,
                          float* __restrict__ mout) {
    constexpr int LPE = IN / 8;
    constexpr int SPLIT = 64 / LPE;
    constexpr int UN = (IN == 64) ? 2 : 1;
    int g = threadIdx.x >> 6;
    int lane = threadIdx.x & 63;
    int node = blockIdx.x * 4 + g;         // grid sized so node < NN always
    int lane_p = lane & (LPE - 1);
    int sub = lane / LPE;

    float acc[8];
#pragma unroll
    for (int i = 0; i < 8; ++i) acc[i] = 0.f;

    int start = row_ptr[node];
    int dg = degI[node];
    const int* cs = csr_src + start;

    int e = sub;
    for (; e + SPLIT * (UN - 1) < dg; e += SPLIT * UN) {
        uint4 u[UN];
#pragma unroll
        for (int j = 0; j < UN; ++j) {
            int s = cs[e + SPLIT * j];
            u[j] = *(const uint4*)(hin + (size_t)s * IN + 8 * lane_p);
        }
#pragma unroll
        for (int j = 0; j < UN; ++j) {
            acc[0] += bflo(u[j].x); acc[1] += bfhi(u[j].x);
            acc[2] += bflo(u[j].y); acc[3] += bfhi(u[j].y);
            acc[4] += bflo(u[j].z); acc[5] += bfhi(u[j].z);
            acc[6] += bflo(u[j].w); acc[7] += bfhi(u[j].w);
        }
    }
    for (; e < dg; e += SPLIT) {
        int s = cs[e];
        uint4 u = *(const uint4*)(hin + (size_t)s * IN + 8 * lane_p);
        acc[0] += bflo(u.x); acc[1] += bfhi(u.x);
        acc[2] += bflo(u.y); acc[3] += bfhi(u.y);
        acc[4] += bflo(u.z); acc[5] += bfhi(u.z);
        acc[6] += bflo(u.w); acc[7] += bfhi(u.w);
    }

    // reduce across the SPLIT sub-groups (lanes LPE apart and up)
#pragma unroll
    for (int m = LPE; m < 64; m <<= 1) {
#pragma unroll
        for (int i = 0; i < 8; ++i) acc[i] += __shfl_xor(acc[i], m);
    }
    if (sub == 0) {
        float r = 1.0f / fmaxf((float)dg, 1.0f);
        float4 v0, v1;
        v0.x = acc[0] * r; v0.y = acc[1] * r; v0.z = acc[2] * r; v0.w = acc[3] * r;
        v1.x = acc[4] * r; v1.y = acc[5] * r; v1.z = acc[6] * r; v1.w = acc[7] * r;
        float* p = mout + (size_t)node * IN + 8 * lane_p;
        *(float4*)p = v0;
        *(float4*)(p + 4) = v1;
    }
}

// ---------- weight prep: f32 [K][64] -> packed bf16 hi/lo B-fragments ----------
__global__ void wprep(const float* __restrict__ Wl0, const float* __restrict__ Wr0,
                      const float* __restrict__ Wl1, const float* __restrict__ Wr1,
                      const float* __restrict__ Wl2, const float* __restrict__ Wr2,
                      const float* __restrict__ W1, unsigned short* __restrict__ out) {
    int b = blockIdx.x;
    int mid, local;
    if (b < 2) { mid = b; local = 0; }                  // K=32 matrices: 1 block each
    else { mid = 2 + (b - 2) / 2; local = (b - 2) & 1; } // K=64 matrices: 2 blocks each
    const float* Ws[8] = {Wl0, Wr0, Wl1, Wr1, Wl2, Wr2, W1, W1 + 64 * 64};
    const int offs[8] = {0, 4096, 8192, 16384, 24576, 32768, 40960, 49152};
    const float* W = Ws[mid];
    int e = local * 256 + threadIdx.x;   // entry = (ks*4+nt)*64 + lane
    int lane = e & 63;
    int fi = e >> 6;                     // ks*4 + nt
    int ks = fi >> 2, nt = fi & 3;
    int lg = lane >> 4, col = lane & 15;
    unsigned short hi[8], lo[8];
#pragma unroll
    for (int j = 0; j < 8; ++j) {
        float w = W[(ks * 32 + lg * 8 + j) * 64 + nt * 16 + col];
        unsigned short h = f2bf(w);
        hi[j] = h;
        lo[j] = f2bf(w - bflo(h));
    }
    unsigned short* dh = out + offs[mid] + ((size_t)(fi * 2 + 0) * 64 + lane) * 8;
    unsigned short* dl = out + offs[mid] + ((size_t)(fi * 2 + 1) * 64 + lane) * 8;
#pragma unroll
    for (int j = 0; j < 8; ++j) { dh[j] = hi[j]; dl[j] = lo[j]; }
}

// ---------- MFMA GEMM: hout = act( mean@Wl + bl + hroot@Wr ) ----------
template <int KIN, bool RELU>
__launch_bounds__(256)
__global__ void sage_gemm(const float* __restrict__ meanv,
                          const unsigned short* __restrict__ hroot,
                          const unsigned short* __restrict__ wl_pk,
                          const unsigned short* __restrict__ wr_pk,
                          const float* __restrict__ bl,
                          unsigned short* __restrict__ hout) {
    constexpr int NKS = KIN / 32;
    int wid = threadIdx.x >> 6, lane = threadIdx.x & 63;
    int tile = blockIdx.x * 4 + wid;
    if (tile >= NN / 16) return;
    int m0 = tile * 16;
    int ar = lane & 15;     // A row / D col
    int lg = lane >> 4;

    bf16x8 ah[NKS];
#pragma unroll
    for (int ks = 0; ks < NKS; ++ks)
        ah[ks] = *(const bf16x8*)(hroot + (size_t)(m0 + ar) * KIN + ks * 32 + lg * 8);

    bf16x8 amh[NKS], aml[NKS];
#pragma unroll
    for (int ks = 0; ks < NKS; ++ks) {
        const float* p = meanv + (size_t)(m0 + ar) * KIN + ks * 32 + lg * 8;
        float4 v0 = *(const float4*)p;
        float4 v1 = *(const float4*)(p + 4);
        float mv[8] = {v0.x, v0.y, v0.z, v0.w, v1.x, v1.y, v1.z, v1.w};
#pragma unroll
        for (int j = 0; j < 8; ++j) {
            unsigned short h = f2bf(mv[j]);
            amh[ks][j] = (short)h;
            aml[ks][j] = (short)f2bf(mv[j] - bflo(h));
        }
    }

#pragma unroll
    for (int nt = 0; nt < 4; ++nt) {
        f32x4 acc = {0.f, 0.f, 0.f, 0.f};
#pragma unroll
        for (int ks = 0; ks < NKS; ++ks) {
            int fi = ks * 4 + nt;
            bf16x8 wlh = *(const bf16x8*)(wl_pk + ((size_t)(fi * 2 + 0) * 64 + lane) * 8);
            bf16x8 wll = *(const bf16x8*)(wl_pk + ((size_t)(fi * 2 + 1) * 64 + lane) * 8);
            bf16x8 wrh = *(const bf16x8*)(wr_pk + ((size_t)(fi * 2 + 0) * 64 + lane) * 8);
            bf16x8 wrl = *(const bf16x8*)(wr_pk + ((size_t)(fi * 2 + 1) * 64 + lane) * 8);
            acc = __builtin_amdgcn_mfma_f32_16x16x32_bf16(amh[ks], wlh, acc, 0, 0, 0);
            acc = __builtin_amdgcn_mfma_f32_16x16x32_bf16(amh[ks], wll, acc, 0, 0, 0);
            acc = __builtin_amdgcn_mfma_f32_16x16x32_bf16(aml[ks], wlh, acc, 0, 0, 0);
            acc = __builtin_amdgcn_mfma_f32_16x16x32_bf16(ah[ks],  wrh, acc, 0, 0, 0);
            acc = __builtin_amdgcn_mfma_f32_16x16x32_bf16(ah[ks],  wrl, acc, 0, 0, 0);
        }
        float b = bl[nt * 16 + ar];
#pragma unroll
        for (int r = 0; r < 4; ++r) {
            float o = acc[r] + b;
            if (RELU) o = fmaxf(o, 0.f);
            hout[(size_t)(m0 + lg * 4 + r) * 64 + nt * 16 + ar] = f2bf(o);
        }
    }
}

// ---------- a1/a2 = h2 @ W1[0:64], h2 @ W1[64:128] ----------
__launch_bounds__(256)
__global__ void pred_gemm(const unsigned short* __restrict__ h2,
                          const unsigned short* __restrict__ wa_pk,
                          const unsigned short* __restrict__ wb_pk,
                          unsigned short* __restrict__ a1,
                          unsigned short* __restrict__ a2) {
    int wid = threadIdx.x >> 6, lane = threadIdx.x & 63;
    int tile = blockIdx.x * 4 + wid;
    if (tile >= NN / 16) return;
    int m0 = tile * 16;
    int ar = lane & 15;
    int lg = lane >> 4;
    bf16x8 ah[2];
#pragma unroll
    for (int ks = 0; ks < 2; ++ks)
        ah[ks] = *(const bf16x8*)(h2 + (size_t)(m0 + ar) * 64 + ks * 32 + lg * 8);
#pragma unroll
    for (int nt = 0; nt < 4; ++nt) {
        f32x4 p = {0.f, 0.f, 0.f, 0.f};
        f32x4 q = {0.f, 0.f, 0.f, 0.f};
#pragma unroll
        for (int ks = 0; ks < 2; ++ks) {
            int fi = ks * 4 + nt;
            bf16x8 wah = *(const bf16x8*)(wa_pk + ((size_t)(fi * 2 + 0) * 64 + lane) * 8);
            bf16x8 wal = *(const bf16x8*)(wa_pk + ((size_t)(fi * 2 + 1) * 64 + lane) * 8);
            bf16x8 wbh = *(const bf16x8*)(wb_pk + ((size_t)(fi * 2 + 0) * 64 + lane) * 8);
            bf16x8 wbl = *(const bf16x8*)(wb_pk + ((size_t)(fi * 2 + 1) * 64 + lane) * 8);
            p = __builtin_amdgcn_mfma_f32_16x16x32_bf16(ah[ks], wah, p, 0, 0, 0);
            p = __builtin_amdgcn_mfma_f32_16x16x32_bf16(ah[ks], wal, p, 0, 0, 0);
            q = __builtin_amdgcn_mfma_f32_16x16x32_bf16(ah[ks], wbh, q, 0, 0, 0);
            q = __builtin_amdgcn_mfma_f32_16x16x32_bf16(ah[ks], wbl, q, 0, 0, 0);
        }
#pragma unroll
        for (int r = 0; r < 4; ++r) {
            size_t off = (size_t)(m0 + lg * 4 + r) * 64 + nt * 16 + ar;
            a1[off] = f2bf(p[r]);
            a2[off] = f2bf(q[r]);
        }
    }
}

// ---------- edge predictor (R4-proven scalar VALU version: one edge per lane) ----------
__launch_bounds__(256)
__global__ void edge_pred(const int* __restrict__ src, const int* __restrict__ dst,
                          const unsigned short* __restrict__ a1, const unsigned short* __restrict__ a2,
                          const float* __restrict__ ea,
                          const float* __restrict__ W1, const float* __restrict__ b1,
                          const float* __restrict__ W2, const float* __restrict__ b2,
                          const float* __restrict__ W3, const float* __restrict__ b3,
                          float* __restrict__ out, int nE) {
    int e = blockIdx.x * blockDim.x + threadIdx.x;
    if (e >= nE) return;
    int s = src[e];
    int d = dst[e];

    const uint4* pa = (const uint4*)(a1 + (size_t)s * 64);
    const uint4* pb = (const uint4*)(a2 + (size_t)d * 64);
    const float4* eav = (const float4*)(ea + (size_t)e * 8);
    float4 v0 = eav[0];
    float4 v1 = eav[1];

    float z1[64];
    const float* wr = W1 + 128 * 64;
#pragma unroll
    for (int j = 0; j < 64; ++j) {
        float a = fmaf(v0.x, wr[j], b1[j]);
        a = fmaf(v0.y, wr[64 + j], a);
        a = fmaf(v0.z, wr[128 + j], a);
        a = fmaf(v0.w, wr[192 + j], a);
        a = fmaf(v1.x, wr[256 + j], a);
        a = fmaf(v1.y, wr[320 + j], a);
        a = fmaf(v1.z, wr[384 + j], a);
        z1[j] = fmaf(v1.w, wr[448 + j], a);
    }

#pragma unroll
    for (int q = 0; q < 8; ++q) {
        uint4 ua = pa[q];
        uint4 ub = pb[q];
        int j0 = q * 8;
        z1[j0 + 0] += bflo(ua.x) + bflo(ub.x);
        z1[j0 + 1] += bfhi(ua.x) + bfhi(ub.x);
        z1[j0 + 2] += bflo(ua.y) + bflo(ub.y);
        z1[j0 + 3] += bfhi(ua.y) + bfhi(ub.y);
        z1[j0 + 4] += bflo(ua.z) + bflo(ub.z);
        z1[j0 + 5] += bfhi(ua.z) + bfhi(ub.z);
        z1[j0 + 6] += bflo(ua.w) + bflo(ub.w);
        z1[j0 + 7] += bfhi(ua.w) + bfhi(ub.w);
    }

    float z2[32];
#pragma unroll
    for (int j = 0; j < 32; ++j) z2[j] = b2[j];
    for (int k = 0; k < 64; ++k) {
        float v = fmaxf(z1[k], 0.0f);
        const float* w = W2 + (size_t)k * 32;
#pragma unroll
        for (int j = 0; j < 32; ++j) z2[j] = fmaf(v, w[j], z2[j]);
    }

    float o = b3[0];
#pragma unroll
    for (int k = 0; k < 32; ++k) o = fmaf(fmaxf(z2[k], 0.0f), W3[k], o);

    out[e] = 1.0f / (1.0f + __expf(-o));
}

extern "C" void kernel_launch(void* const* d_in, const int* in_sizes, int n_in,
                              void* d_out, int out_size, void* d_ws, size_t ws_size,
                              hipStream_t stream) {
    const float* x   = (const float*)d_in[0];
    const int*   ei  = (const int*)d_in[1];
    const float* ea  = (const float*)d_in[2];
    const float* Wl0 = (const float*)d_in[3];
    const float* bl0 = (const float*)d_in[4];
    const float* Wr0 = (const float*)d_in[5];
    const float* Wl1 = (const float*)d_in[6];
    const float* bl1 = (const float*)d_in[7];
    const float* Wr1 = (const float*)d_in[8];
    const float* Wl2 = (const float*)d_in[9];
    const float* bl2 = (const float*)d_in[10];
    const float* Wr2 = (const float*)d_in[11];
    const float* W1  = (const float*)d_in[12];
    const float* b1  = (const float*)d_in[13];
    const float* W2  = (const float*)d_in[14];
    const float* b2  = (const float*)d_in[15];
    const float* W3  = (const float*)d_in[16];
    const float* b3  = (const float*)d_in[17];

    const int* src = ei;
    const int* dst = ei + NE;

    char* ws = (char*)d_ws;
    size_t off = 0;
    auto alloc = [&](size_t bytes) {
        void* p = ws + off;
        off += (bytes + 255) & ~(size_t)255;
        return p;
    };
    unsigned short* xb = (unsigned short*)alloc((size_t)NN * 32 * 2);
    unsigned short* hA = (unsigned short*)alloc((size_t)NN * HID * 2);  // layer0 out; reused as h2
    unsigned short* hB = (unsigned short*)alloc((size_t)NN * HID * 2);  // layer1 out
    unsigned short* a1 = (unsigned short*)alloc((size_t)NN * HID * 2);
    unsigned short* a2 = (unsigned short*)alloc((size_t)NN * HID * 2);
    unsigned short* wpk = (unsigned short*)alloc((size_t)57344 * 2);
    int* degI    = (int*)alloc(NN * sizeof(int));
    int* row_ptr = (int*)alloc(NN * sizeof(int));
    int* rowtmp  = (int*)alloc(NN * sizeof(int));
    int* cursor  = (int*)alloc(NN * sizeof(int));
    int* blockSum= (int*)alloc(512 * sizeof(int));
    int* blockOff= (int*)alloc(512 * sizeof(int));
    int* csr_src = (int*)alloc((size_t)NE * sizeof(int));
    // meanv aliases [a1|a2] (25.6MB): all mean reads complete before pred_gemm writes a1/a2
    float* meanv = (float*)a1;
    float* out = (float*)d_out;

    const int BS = 256;
    dim3 blkE((NE + BS - 1) / BS);
    int n4 = NN * 32 / 4;
    int gemm_blk = (NN / 16 + 3) / 4;   // 1563

    // ---- x -> bf16 + CSR build + weight prep ----
    hipMemsetAsync(degI, 0, NN * sizeof(int), stream);
    xcast<<<(n4 + BS - 1) / BS, BS, 0, stream>>>(x, xb, n4);
    count_kernel<<<blkE, BS, 0, stream>>>(dst, degI, NE);
    scan1_kernel<<<NBLK, SCAN_BS, 0, stream>>>(degI, rowtmp, blockSum);
    scan2_kernel<<<1, 512, 0, stream>>>(blockSum, blockOff, NBLK);
    scan3_kernel<<<NBLK, SCAN_BS, 0, stream>>>(rowtmp, blockOff, row_ptr, cursor);
    fill_kernel<<<NSLICE * FCHUNK, BS, 0, stream>>>(src, dst, cursor, csr_src, NE);
    wprep<<<14, 256, 0, stream>>>(Wl0, Wr0, Wl1, Wr1, Wl2, Wr2, W1, wpk);

    // ---- layer 0 ----
    aggregate<32><<<NN / 4, 256, 0, stream>>>(row_ptr, degI, csr_src, xb, meanv);
    sage_gemm<32, true><<<gemm_blk, 256, 0, stream>>>(meanv, xb, wpk + 0, wpk + 4096, bl0, hA);
    // ---- layer 1 ----
    aggregate<64><<<NN / 4, 256, 0, stream>>>(row_ptr, degI, csr_src, hA, meanv);
    sage_gemm<64, true><<<gemm_blk, 256, 0, stream>>>(meanv, hA, wpk + 8192, wpk + 16384, bl1, hB);
    // ---- layer 2 (no ReLU) ----
    aggregate<64><<<NN / 4, 256, 0, stream>>>(row_ptr, degI, csr_src, hB, meanv);
    sage_gemm<64, false><<<gemm_blk, 256, 0, stream>>>(meanv, hB, wpk + 24576, wpk + 32768, bl2, hA);
    // ---- a1/a2 = h2 @ W1 halves ----
    pred_gemm<<<gemm_blk, 256, 0, stream>>>(hA, wpk + 40960, wpk + 49152, a1, a2);

    // ---- edge predictor (VALU, one edge per lane) ----
    edge_pred<<<blkE, BS, 0, stream>>>(src, dst, a1, a2, ea, W1, b1, W2, b2, W3, b3, out, NE);
}